// Round 4
// baseline (347.424 us; speedup 1.0000x reference)
//
#include <hip/hip_runtime.h>
#include <math.h>

#define EPS 1.55e-05f
#define PIX 36864   // 4*96*96
#define IMG 9216    // 96*96

typedef __attribute__((ext_vector_type(8))) short short8v;
typedef __attribute__((ext_vector_type(4))) float float4v;
typedef __attribute__((ext_vector_type(4))) unsigned short ushort4v;

static __device__ __forceinline__ unsigned short f2bf(float f) {
    unsigned u = __float_as_uint(f);
    unsigned r = (u + 0x7FFFu + ((u >> 16) & 1u)) >> 16;
    return (unsigned short)r;
}
static __device__ __forceinline__ float b2f(unsigned short h) {
    return __uint_as_float(((unsigned)h) << 16);
}

// ---------------- relative position bias (6 heads x 9 taps) ----------------
__global__ __launch_bounds__(512)
void relbias_kernel(const float* __restrict__ w1, const float* __restrict__ b1,
                    const float* __restrict__ w2, float* __restrict__ rb)
{
    __shared__ float hid[9][512];
    int i = threadIdx.x;
    const float s0 = -0.7739760316291208f, s2 = 0.7739760316291208f;
    float sv[3]; sv[0] = s0; sv[1] = 0.f; sv[2] = s2;
    float w1a = w1[i], w1b = w1[512 + i], bb = b1[i];
    #pragma unroll
    for (int j = 0; j < 9; j++) {
        float t0 = sv[j / 3], t1 = sv[j % 3];
        hid[j][i] = fmaxf(t0 * w1a + t1 * w1b + bb, 0.f);
    }
    __syncthreads();
    if (i < 54) {
        int he = i / 9, t = i % 9, j = 8 - t;
        float acc = 0.f;
        for (int u = 0; u < 512; u++) acc += hid[j][u] * w2[u * 6 + he];
        rb[he * 9 + t] = 16.f / (1.f + expf(-acc));
    }
}

// ---------------- prep: x->bf16, qkv_w^T->bf16, proj_w^T->bf16 ----------------
__global__ __launch_bounds__(256)
void prep_kernel(const float* __restrict__ x, const float* __restrict__ qkv_w,
                 const float* __restrict__ proj_w,
                 unsigned short* __restrict__ xs, unsigned short* __restrict__ Bt,
                 unsigned short* __restrict__ Bt2)
{
    int tid = blockIdx.x * 256 + threadIdx.x;
    int stride = gridDim.x * 256;
    int total_x4 = PIX * 192 / 4;
    for (int i = tid; i < total_x4; i += stride) {
        float4 v = ((const float4*)x)[i];
        ushort4v o;
        o.x = f2bf(v.x); o.y = f2bf(v.y); o.z = f2bf(v.z); o.w = f2bf(v.w);
        ((ushort4v*)xs)[i] = o;
    }
    for (int i = tid; i < 576 * 192; i += stride) {
        int n = i / 192, k = i - n * 192;
        Bt[i] = f2bf(qkv_w[k * 576 + n]);
    }
    for (int i = tid; i < 192 * 192; i += stride) {
        int n = i / 192, k = i - n * 192;
        Bt2[i] = f2bf(proj_w[k * 192 + n]);
    }
}

// ---------------- MFMA bf16 GEMM: C = A(MxK=192) * Bt^T + bias ----------------
// A: [M][192] bf16 row-major. Bt: [N][192] bf16 (n-major, k contiguous).
// MODE 0: store C^T as bf16 planes [n][PIX] with qkv bias.  MODE 1: store fp32 [m][192] + bias.
template<int MODE>
__global__ __launch_bounds__(256)
void mfma_gemm_kernel(const unsigned short* __restrict__ Abf,
                      const unsigned short* __restrict__ Btb,
                      void* __restrict__ Cout,
                      const float* __restrict__ bias0,
                      const float* __restrict__ bias1)
{
    const int K = 192;
    __shared__ short As[128 * 64];   // [row][k-chunk, XOR-swizzled 16B granules]
    __shared__ short Bs[64 * 64];
    int tid = threadIdx.x;
    int m0 = blockIdx.y * 128;
    int n0 = blockIdx.x * 64;
    int lane = tid & 63, wid = tid >> 6;
    int wm = wid >> 1, wn = wid & 1;
    int lr = lane & 15, lk = lane >> 4;

    float4v acc[4][2];
    #pragma unroll
    for (int a = 0; a < 4; a++)
        #pragma unroll
        for (int b = 0; b < 2; b++)
            #pragma unroll
            for (int e = 0; e < 4; e++) acc[a][b][e] = 0.f;

    int sr = tid >> 3;          // 0..31
    int sc = tid & 7;           // 0..7 (16B chunk)
    for (int k0 = 0; k0 < K; k0 += 64) {
        #pragma unroll
        for (int i = 0; i < 4; i++) {
            int r = sr + i * 32;
            short8v v = *(const short8v*)(Abf + (size_t)(m0 + r) * K + k0 + sc * 8);
            *(short8v*)(As + r * 64 + ((sc ^ (r & 7)) * 8)) = v;
        }
        #pragma unroll
        for (int i = 0; i < 2; i++) {
            int r = sr + i * 32;
            short8v v = *(const short8v*)(Btb + (size_t)(n0 + r) * K + k0 + sc * 8);
            *(short8v*)(Bs + r * 64 + ((sc ^ (r & 7)) * 8)) = v;
        }
        __syncthreads();
        #pragma unroll
        for (int ks = 0; ks < 2; ks++) {
            short8v af[4], bf[2];
            #pragma unroll
            for (int fm = 0; fm < 4; fm++) {
                int r = wm * 64 + fm * 16 + lr;
                int c = (ks * 4 + lk) ^ (r & 7);
                af[fm] = *(const short8v*)(As + r * 64 + c * 8);
            }
            #pragma unroll
            for (int fn = 0; fn < 2; fn++) {
                int r = wn * 32 + fn * 16 + lr;
                int c = (ks * 4 + lk) ^ (r & 7);
                bf[fn] = *(const short8v*)(Bs + r * 64 + c * 8);
            }
            #pragma unroll
            for (int fm = 0; fm < 4; fm++)
                #pragma unroll
                for (int fn = 0; fn < 2; fn++)
                    acc[fm][fn] = __builtin_amdgcn_mfma_f32_16x16x32_bf16(
                        af[fm], bf[fn], acc[fm][fn], 0, 0, 0);
        }
        __syncthreads();
    }

    if (MODE == 0) {
        unsigned short* qkvT = (unsigned short*)Cout;
        #pragma unroll
        for (int fm = 0; fm < 4; fm++) {
            int m = m0 + wm * 64 + fm * 16 + lk * 4;
            #pragma unroll
            for (int fn = 0; fn < 2; fn++) {
                int n = n0 + wn * 32 + fn * 16 + lr;
                float bv = (n < 192) ? bias0[n] : ((n < 384) ? 0.f : bias1[n - 384]);
                ushort4v o;
                #pragma unroll
                for (int e = 0; e < 4; e++) o[e] = f2bf(acc[fm][fn][e] + bv);
                *(ushort4v*)(qkvT + (size_t)n * PIX + m) = o;
            }
        }
    } else {
        float* outp = (float*)Cout;
        #pragma unroll
        for (int fm = 0; fm < 4; fm++) {
            #pragma unroll
            for (int fn = 0; fn < 2; fn++) {
                int n = n0 + wn * 32 + fn * 16 + lr;
                float bv = bias0[n];
                #pragma unroll
                for (int e = 0; e < 4; e++) {
                    int m = m0 + wm * 64 + fm * 16 + lk * 4 + e;
                    outp[(size_t)m * 192 + n] = acc[fm][fn][e] + bv;
                }
            }
        }
    }
}

// ---------------- fused: depthwise(k,v) + cosine attention + PV -----------------------
// One wave per (head, 32x2 pixel tile). Lane = pixel (32 x-contig, 2 rows). bf16 I/O.
__global__ __launch_bounds__(64)
void fused3_kernel(const unsigned short* __restrict__ qkvT, const float* __restrict__ deform,
                   const float* __restrict__ scale, const float* __restrict__ rb,
                   unsigned short* __restrict__ attnS)
{
    __shared__ float vbuf[64][33];
    int id = blockIdx.x;              // 4 b * 6 he * 48 ypairs * 3 strips
    int strip = id % 3;
    int yp = (id / 3) % 48;
    int he = (id / 144) % 6;
    int b = id / 864;
    int l = threadIdx.x;
    int X = strip * 32 + (l & 31);
    int Y = yp * 2 + (l >> 5);
    int pimg = Y * 96 + X;
    size_t ibase = (size_t)b * IMG;

    int off[9];
    unsigned okm = 0;
    #pragma unroll
    for (int pos = 0; pos < 9; pos++) {
        int dy = pos / 3 - 1, dx = pos % 3 - 1;
        int yy = Y + dy, xx = X + dx;
        bool ok = (yy >= 0) && (yy < 96) && (xx >= 0) && (xx < 96);
        okm |= (ok ? 1u : 0u) << pos;
        off[pos] = ok ? (yy * 96 + xx) : pimg;
    }

    float qk[9], kn[9];
    #pragma unroll
    for (int t = 0; t < 9; t++) { qk[t] = 0.f; kn[t] = 0.f; }
    float qn2 = 0.f;

    for (int ci = 0; ci < 32; ci++) {
        int c = he * 32 + ci;
        const unsigned short* qrow = qkvT + (size_t)c * PIX + ibase;
        const unsigned short* krow = qkvT + (size_t)(192 + c) * PIX + ibase;
        float q = b2f(qrow[pimg]);
        qn2 = fmaf(q, q, qn2);
        float kin[9];
        #pragma unroll
        for (int pos = 0; pos < 9; pos++)
            kin[pos] = ((okm >> pos) & 1) ? b2f(krow[off[pos]]) : 0.f;
        float ktap[9];
        #pragma unroll
        for (int t = 0; t < 9; t++) ktap[t] = kin[t];
        #pragma unroll
        for (int pos = 0; pos < 9; pos++) {
            const float* wr = deform + ((size_t)pos * 192 + c) * 9;
            #pragma unroll
            for (int t = 0; t < 9; t++) ktap[t] = fmaf(kin[pos], wr[t], ktap[t]);
        }
        #pragma unroll
        for (int t = 0; t < 9; t++) {
            qk[t] = fmaf(q, ktap[t], qk[t]);
            kn[t] = fmaf(ktap[t], ktap[t], kn[t]);
        }
    }

    float qn = rsqrtf(fmaxf(qn2, EPS));
    float es = expf(scale[he]);
    float w[9];
    float m = -1e30f;
    #pragma unroll
    for (int t = 0; t < 9; t++) {
        float lg = es * qn * qk[t] * rsqrtf(fmaxf(kn[t], EPS));
        lg += (((okm >> t) & 1) ? 0.f : -100.f) + rb[he * 9 + t];
        w[t] = lg;
        m = fmaxf(m, lg);
    }
    float ssum = 0.f;
    #pragma unroll
    for (int t = 0; t < 9; t++) { w[t] = expf(w[t] - m); ssum += w[t]; }
    float inv = 1.f / ssum;
    #pragma unroll
    for (int t = 0; t < 9; t++) w[t] *= inv;

    for (int ci = 0; ci < 32; ci++) {
        int c = he * 32 + ci;
        const unsigned short* vrow = qkvT + (size_t)(384 + c) * PIX + ibase;
        float vin[9];
        #pragma unroll
        for (int pos = 0; pos < 9; pos++)
            vin[pos] = ((okm >> pos) & 1) ? b2f(vrow[off[pos]]) : 0.f;
        float acc = 0.f;
        #pragma unroll
        for (int pos = 0; pos < 9; pos++) {
            const float* wr = deform + ((size_t)pos * 192 + c) * 9;
            float sp = w[pos];
            #pragma unroll
            for (int t = 0; t < 9; t++) sp = fmaf(w[t], wr[t], sp);
            acc = fmaf(vin[pos], sp, acc);
        }
        vbuf[l][ci] = acc;
    }
    // per-lane transpose buffer -> row-major bf16 store (64B per pixel, aligned)
    unsigned short* orow = attnS + (ibase + pimg) * 192 + he * 32;
    #pragma unroll
    for (int j = 0; j < 8; j++) {
        ushort4v o;
        #pragma unroll
        for (int e = 0; e < 4; e++) o[e] = f2bf(vbuf[l][j * 4 + e]);
        *(ushort4v*)(orow + j * 4) = o;
    }
}

extern "C" void kernel_launch(void* const* d_in, const int* in_sizes, int n_in,
                              void* d_out, int out_size, void* d_ws, size_t ws_size,
                              hipStream_t stream) {
    const float* x       = (const float*)d_in[0];
    const float* qkv_w   = (const float*)d_in[1];
    const float* q_bias  = (const float*)d_in[2];
    const float* v_bias  = (const float*)d_in[3];
    const float* deform  = (const float*)d_in[4];
    const float* scale   = (const float*)d_in[5];
    const float* cpb_w1  = (const float*)d_in[6];
    const float* cpb_b1  = (const float*)d_in[7];
    const float* cpb_w2  = (const float*)d_in[8];
    const float* proj_w  = (const float*)d_in[9];
    const float* proj_b  = (const float*)d_in[10];
    float* out = (float*)d_out;

    char* ws = (char*)d_ws;
    float*          rb    = (float*)ws;                               // 256 B
    unsigned short* xs    = (unsigned short*)(ws + 256);              // PIX*192*2 = 14,155,776 B
    unsigned short* Bt    = (unsigned short*)(ws + 256 + 14155776);   // 576*192*2 = 221,184 B
    unsigned short* Bt2   = (unsigned short*)(ws + 256 + 14155776 + 221184);          // 73,728 B
    unsigned short* qkvT  = (unsigned short*)(ws + 256 + 14155776 + 221184 + 73728);  // 576*PIX*2 = 42,467,328 B
    unsigned short* attnS = (unsigned short*)(ws + 256 + 14155776 + 221184 + 73728 + 42467328); // 14,155,776 B

    relbias_kernel<<<1, 512, 0, stream>>>(cpb_w1, cpb_b1, cpb_w2, rb);
    prep_kernel<<<2048, 256, 0, stream>>>(x, qkv_w, proj_w, xs, Bt, Bt2);
    mfma_gemm_kernel<0><<<dim3(576 / 64, PIX / 128), 256, 0, stream>>>(
        xs, Bt, (void*)qkvT, q_bias, v_bias);
    fused3_kernel<<<4 * 6 * 48 * 3, 64, 0, stream>>>(qkvT, deform, scale, rb, attnS);
    mfma_gemm_kernel<1><<<dim3(192 / 64, PIX / 128), 256, 0, stream>>>(
        attnS, Bt2, (void*)out, proj_b, nullptr);
}

// Round 5
// 340.408 us; speedup vs baseline: 1.0206x; 1.0206x over previous
//
#include <hip/hip_runtime.h>
#include <math.h>

#define EPS 1.55e-05f
#define PIX 36864   // 4*96*96
#define IMG 9216    // 96*96

typedef __attribute__((ext_vector_type(8))) short short8v;
typedef __attribute__((ext_vector_type(4))) float float4v;
typedef __attribute__((ext_vector_type(4))) unsigned short ushort4v;

static __device__ __forceinline__ unsigned short f2bf(float f) {
    unsigned u = __float_as_uint(f);
    unsigned r = (u + 0x7FFFu + ((u >> 16) & 1u)) >> 16;
    return (unsigned short)r;
}
static __device__ __forceinline__ float b2f(unsigned short h) {
    return __uint_as_float(((unsigned)h) << 16);
}

// ---------------- relative position bias (6 heads x 9 taps) ----------------
__global__ __launch_bounds__(512)
void relbias_kernel(const float* __restrict__ w1, const float* __restrict__ b1,
                    const float* __restrict__ w2, float* __restrict__ rb)
{
    __shared__ float hid[9][512];
    int i = threadIdx.x;
    const float s0 = -0.7739760316291208f, s2 = 0.7739760316291208f;
    float sv[3]; sv[0] = s0; sv[1] = 0.f; sv[2] = s2;
    float w1a = w1[i], w1b = w1[512 + i], bb = b1[i];
    #pragma unroll
    for (int j = 0; j < 9; j++) {
        float t0 = sv[j / 3], t1 = sv[j % 3];
        hid[j][i] = fmaxf(t0 * w1a + t1 * w1b + bb, 0.f);
    }
    __syncthreads();
    if (i < 54) {
        int he = i / 9, t = i % 9, j = 8 - t;
        float acc = 0.f;
        for (int u = 0; u < 512; u++) acc += hid[j][u] * w2[u * 6 + he];
        rb[he * 9 + t] = 16.f / (1.f + expf(-acc));
    }
}

// ---------------- prep: x->bf16, qkv_w^T->bf16, proj_w^T->bf16 ----------------
__global__ __launch_bounds__(256)
void prep_kernel(const float* __restrict__ x, const float* __restrict__ qkv_w,
                 const float* __restrict__ proj_w,
                 unsigned short* __restrict__ xs, unsigned short* __restrict__ Bt,
                 unsigned short* __restrict__ Bt2)
{
    int tid = blockIdx.x * 256 + threadIdx.x;
    int stride = gridDim.x * 256;
    int total_x4 = PIX * 192 / 4;
    for (int i = tid; i < total_x4; i += stride) {
        float4 v = ((const float4*)x)[i];
        ushort4v o;
        o.x = f2bf(v.x); o.y = f2bf(v.y); o.z = f2bf(v.z); o.w = f2bf(v.w);
        ((ushort4v*)xs)[i] = o;
    }
    for (int i = tid; i < 576 * 192; i += stride) {
        int n = i / 192, k = i - n * 192;
        Bt[i] = f2bf(qkv_w[k * 576 + n]);
    }
    for (int i = tid; i < 192 * 192; i += stride) {
        int n = i / 192, k = i - n * 192;
        Bt2[i] = f2bf(proj_w[k * 192 + n]);
    }
}

// ---------------- MFMA bf16 GEMM: C = A(MxK=192) * Bt^T + bias ----------------
// A: [M][192] bf16 row-major. Bt: [N][192] bf16 (n-major, k contiguous).
// MODE 0: store C^T as bf16 planes [n][PIX] (LDS-transposed, coalesced) + qkv bias.
// MODE 1: store fp32 [m][192] + bias.
template<int MODE>
__global__ __launch_bounds__(256)
void mfma_gemm_kernel(const unsigned short* __restrict__ Abf,
                      const unsigned short* __restrict__ Btb,
                      void* __restrict__ Cout,
                      const float* __restrict__ bias0,
                      const float* __restrict__ bias1)
{
    const int K = 192;
    __shared__ short smem[128 * 64 + 64 * 64];   // As | Bs ; reused as epilogue buffer
    short* As = smem;
    short* Bs = smem + 128 * 64;
    int tid = threadIdx.x;
    int m0 = blockIdx.y * 128;
    int n0 = blockIdx.x * 64;
    int lane = tid & 63, wid = tid >> 6;
    int wm = wid >> 1, wn = wid & 1;
    int lr = lane & 15, lk = lane >> 4;

    float4v acc[4][2];
    #pragma unroll
    for (int a = 0; a < 4; a++)
        #pragma unroll
        for (int b = 0; b < 2; b++)
            #pragma unroll
            for (int e = 0; e < 4; e++) acc[a][b][e] = 0.f;

    int sr = tid >> 3;          // 0..31
    int sc = tid & 7;           // 0..7 (16B chunk)
    for (int k0 = 0; k0 < K; k0 += 64) {
        #pragma unroll
        for (int i = 0; i < 4; i++) {
            int r = sr + i * 32;
            short8v v = *(const short8v*)(Abf + (size_t)(m0 + r) * K + k0 + sc * 8);
            *(short8v*)(As + r * 64 + ((sc ^ (r & 7)) * 8)) = v;
        }
        #pragma unroll
        for (int i = 0; i < 2; i++) {
            int r = sr + i * 32;
            short8v v = *(const short8v*)(Btb + (size_t)(n0 + r) * K + k0 + sc * 8);
            *(short8v*)(Bs + r * 64 + ((sc ^ (r & 7)) * 8)) = v;
        }
        __syncthreads();
        #pragma unroll
        for (int ks = 0; ks < 2; ks++) {
            short8v af[4], bf[2];
            #pragma unroll
            for (int fm = 0; fm < 4; fm++) {
                int r = wm * 64 + fm * 16 + lr;
                int c = (ks * 4 + lk) ^ (r & 7);
                af[fm] = *(const short8v*)(As + r * 64 + c * 8);
            }
            #pragma unroll
            for (int fn = 0; fn < 2; fn++) {
                int r = wn * 32 + fn * 16 + lr;
                int c = (ks * 4 + lk) ^ (r & 7);
                bf[fn] = *(const short8v*)(Bs + r * 64 + c * 8);
            }
            #pragma unroll
            for (int fm = 0; fm < 4; fm++)
                #pragma unroll
                for (int fn = 0; fn < 2; fn++)
                    acc[fm][fn] = __builtin_amdgcn_mfma_f32_16x16x32_bf16(
                        af[fm], bf[fn], acc[fm][fn], 0, 0, 0);
        }
        __syncthreads();
    }

    if (MODE == 0) {
        // stage C tile (bf16) into LDS as [n 0..63][m 0..127] with row pad 136
        unsigned short* T = (unsigned short*)smem;
        #pragma unroll
        for (int fm = 0; fm < 4; fm++) {
            int m = wm * 64 + fm * 16 + lk * 4;
            #pragma unroll
            for (int fn = 0; fn < 2; fn++) {
                int n = wn * 32 + fn * 16 + lr;
                float bv;
                {
                    int gn = n0 + n;
                    bv = (gn < 192) ? bias0[gn] : ((gn < 384) ? 0.f : bias1[gn - 384]);
                }
                ushort4v o;
                #pragma unroll
                for (int e = 0; e < 4; e++) o[e] = f2bf(acc[fm][fn][e] + bv);
                *(ushort4v*)(T + n * 136 + m) = o;
            }
        }
        __syncthreads();
        unsigned short* qkvT = (unsigned short*)Cout;
        #pragma unroll
        for (int i = 0; i < 4; i++) {
            int u = tid + 256 * i;            // 0..1023
            int n = u >> 4, mc = u & 15;
            short8v vv = *(const short8v*)(T + n * 136 + mc * 8);
            *(short8v*)(qkvT + (size_t)(n0 + n) * PIX + m0 + mc * 8) = vv;
        }
    } else {
        float* outp = (float*)Cout;
        #pragma unroll
        for (int fm = 0; fm < 4; fm++) {
            #pragma unroll
            for (int fn = 0; fn < 2; fn++) {
                int n = n0 + wn * 32 + fn * 16 + lr;
                float bv = bias0[n];
                #pragma unroll
                for (int e = 0; e < 4; e++) {
                    int m = m0 + wm * 64 + fm * 16 + lk * 4 + e;
                    outp[(size_t)m * 192 + n] = acc[fm][fn][e] + bv;
                }
            }
        }
    }
}

// ---------------- fused: depthwise(k,v) + cosine attention + PV -----------------------
// Block = 256 thr = 4 waves per (head, 32x2 pixel tile). Wave w handles channels
// w*8..w*8+7; per-head reductions combined via LDS float atomics. Lane (0..63) = pixel.
__global__ __launch_bounds__(256)
void fused4_kernel(const unsigned short* __restrict__ qkvT, const float* __restrict__ deform,
                   const float* __restrict__ scale, const float* __restrict__ rb,
                   unsigned short* __restrict__ attnS)
{
    __shared__ float red[64][21];   // per-pixel: qk[0..8], kn[9..17], qn2[18]

    int id = blockIdx.x;              // 4 b * 6 he * 48 ypairs * 3 strips = 3456
    int strip = id % 3;
    int yp = (id / 3) % 48;
    int he = (id / 144) % 6;
    int b = id / 864;
    int tid = threadIdx.x;
    int l = tid & 63;
    int wsub = tid >> 6;              // 0..3 channel-split
    int X = strip * 32 + (l & 31);
    int Y = yp * 2 + (l >> 5);
    int pimg = Y * 96 + X;
    size_t ibase = (size_t)b * IMG;

    for (int i = tid; i < 64 * 21; i += 256) (&red[0][0])[i] = 0.f;
    __syncthreads();

    int cbase = __builtin_amdgcn_readfirstlane(he * 32 + wsub * 8);

    int off[9];
    unsigned okm = 0;
    #pragma unroll
    for (int pos = 0; pos < 9; pos++) {
        int dy = pos / 3 - 1, dx = pos % 3 - 1;
        int yy = Y + dy, xx = X + dx;
        bool ok = (yy >= 0) && (yy < 96) && (xx >= 0) && (xx < 96);
        okm |= (ok ? 1u : 0u) << pos;
        off[pos] = ok ? (yy * 96 + xx) : pimg;
    }

    float qk[9], kn[9];
    #pragma unroll
    for (int t = 0; t < 9; t++) { qk[t] = 0.f; kn[t] = 0.f; }
    float qn2 = 0.f;

    // ---- pass 1: 8 channels of k depthwise + partial reductions ----
    for (int ci = 0; ci < 8; ci++) {
        int c = cbase + ci;
        const unsigned short* qrow = qkvT + (size_t)c * PIX + ibase;
        const unsigned short* krow = qkvT + (size_t)(192 + c) * PIX + ibase;
        float q = b2f(qrow[pimg]);
        qn2 = fmaf(q, q, qn2);
        float kin[9];
        #pragma unroll
        for (int pos = 0; pos < 9; pos++)
            kin[pos] = ((okm >> pos) & 1) ? b2f(krow[off[pos]]) : 0.f;
        float ktap[9];
        #pragma unroll
        for (int t = 0; t < 9; t++) ktap[t] = kin[t];
        #pragma unroll
        for (int pos = 0; pos < 9; pos++) {
            const float* wr = deform + ((size_t)pos * 192 + c) * 9;   // wave-uniform
            #pragma unroll
            for (int t = 0; t < 9; t++) ktap[t] = fmaf(kin[pos], wr[t], ktap[t]);
        }
        #pragma unroll
        for (int t = 0; t < 9; t++) {
            qk[t] = fmaf(q, ktap[t], qk[t]);
            kn[t] = fmaf(ktap[t], ktap[t], kn[t]);
        }
    }

    #pragma unroll
    for (int t = 0; t < 9; t++) atomicAdd(&red[l][t], qk[t]);
    #pragma unroll
    for (int t = 0; t < 9; t++) atomicAdd(&red[l][9 + t], kn[t]);
    atomicAdd(&red[l][18], qn2);
    __syncthreads();

    // ---- softmax (redundant per wave, identical inputs) ----
    float qn = rsqrtf(fmaxf(red[l][18], EPS));
    float es = expf(scale[he]);
    float w[9];
    float m = -1e30f;
    #pragma unroll
    for (int t = 0; t < 9; t++) {
        float lg = es * qn * red[l][t] * rsqrtf(fmaxf(red[l][9 + t], EPS));
        lg += (((okm >> t) & 1) ? 0.f : -100.f) + rb[he * 9 + t];
        w[t] = lg;
        m = fmaxf(m, lg);
    }
    float ssum = 0.f;
    #pragma unroll
    for (int t = 0; t < 9; t++) { w[t] = expf(w[t] - m); ssum += w[t]; }
    float inv = 1.f / ssum;
    #pragma unroll
    for (int t = 0; t < 9; t++) w[t] *= inv;

    // ---- pass 2: 8 channels of v depthwise folded through softmax weights ----
    unsigned short o8[8];
    for (int ci = 0; ci < 8; ci++) {
        int c = cbase + ci;
        const unsigned short* vrow = qkvT + (size_t)(384 + c) * PIX + ibase;
        float vin[9];
        #pragma unroll
        for (int pos = 0; pos < 9; pos++)
            vin[pos] = ((okm >> pos) & 1) ? b2f(vrow[off[pos]]) : 0.f;
        float acc = 0.f;
        #pragma unroll
        for (int pos = 0; pos < 9; pos++) {
            const float* wr = deform + ((size_t)pos * 192 + c) * 9;   // wave-uniform
            float sp = w[pos];
            #pragma unroll
            for (int t = 0; t < 9; t++) sp = fmaf(w[t], wr[t], sp);
            acc = fmaf(vin[pos], sp, acc);
        }
        o8[ci] = f2bf(acc);
    }
    // 16B contiguous store per lane: channels cbase..cbase+7 of this pixel
    short8v ov;
    #pragma unroll
    for (int ci = 0; ci < 8; ci++) ov[ci] = (short)o8[ci];
    *(short8v*)(attnS + (ibase + pimg) * 192 + cbase) = ov;
}

extern "C" void kernel_launch(void* const* d_in, const int* in_sizes, int n_in,
                              void* d_out, int out_size, void* d_ws, size_t ws_size,
                              hipStream_t stream) {
    const float* x       = (const float*)d_in[0];
    const float* qkv_w   = (const float*)d_in[1];
    const float* q_bias  = (const float*)d_in[2];
    const float* v_bias  = (const float*)d_in[3];
    const float* deform  = (const float*)d_in[4];
    const float* scale   = (const float*)d_in[5];
    const float* cpb_w1  = (const float*)d_in[6];
    const float* cpb_b1  = (const float*)d_in[7];
    const float* cpb_w2  = (const float*)d_in[8];
    const float* proj_w  = (const float*)d_in[9];
    const float* proj_b  = (const float*)d_in[10];
    float* out = (float*)d_out;

    char* ws = (char*)d_ws;
    float*          rb    = (float*)ws;                               // 256 B
    unsigned short* xs    = (unsigned short*)(ws + 256);              // PIX*192*2 = 14,155,776 B
    unsigned short* Bt    = (unsigned short*)(ws + 256 + 14155776);   // 576*192*2 = 221,184 B
    unsigned short* Bt2   = (unsigned short*)(ws + 256 + 14155776 + 221184);          // 73,728 B
    unsigned short* qkvT  = (unsigned short*)(ws + 256 + 14155776 + 221184 + 73728);  // 576*PIX*2 = 42,467,328 B
    unsigned short* attnS = (unsigned short*)(ws + 256 + 14155776 + 221184 + 73728 + 42467328); // 14,155,776 B

    relbias_kernel<<<1, 512, 0, stream>>>(cpb_w1, cpb_b1, cpb_w2, rb);
    prep_kernel<<<2048, 256, 0, stream>>>(x, qkv_w, proj_w, xs, Bt, Bt2);
    mfma_gemm_kernel<0><<<dim3(576 / 64, PIX / 128), 256, 0, stream>>>(
        xs, Bt, (void*)qkvT, q_bias, v_bias);
    fused4_kernel<<<3456, 256, 0, stream>>>(qkvT, deform, scale, rb, attnS);
    mfma_gemm_kernel<1><<<dim3(192 / 64, PIX / 128), 256, 0, stream>>>(
        attnS, Bt2, (void*)out, proj_b, nullptr);
}

// Round 6
// 291.925 us; speedup vs baseline: 1.1901x; 1.1661x over previous
//
#include <hip/hip_runtime.h>
#include <math.h>

#define EPS 1.55e-05f
#define PIX 36864   // 4*96*96
#define IMG 9216    // 96*96

typedef __attribute__((ext_vector_type(8))) short short8v;
typedef __attribute__((ext_vector_type(4))) float float4v;
typedef __attribute__((ext_vector_type(4))) unsigned short ushort4v;
typedef __attribute__((ext_vector_type(4))) unsigned int uint4v;

static __device__ __forceinline__ unsigned short f2bf(float f) {
    unsigned u = __float_as_uint(f);
    unsigned r = (u + 0x7FFFu + ((u >> 16) & 1u)) >> 16;
    return (unsigned short)r;
}
static __device__ __forceinline__ float bflo(unsigned d) {   // even channel (low 16)
    return __uint_as_float(d << 16);
}
static __device__ __forceinline__ float bfhi(unsigned d) {   // odd channel (high 16)
    return __uint_as_float(d & 0xffff0000u);
}

// ---------------- relative position bias (6 heads x 9 taps) ----------------
__global__ __launch_bounds__(512)
void relbias_kernel(const float* __restrict__ w1, const float* __restrict__ b1,
                    const float* __restrict__ w2, float* __restrict__ rb)
{
    __shared__ float hid[9][512];
    int i = threadIdx.x;
    const float s0 = -0.7739760316291208f, s2 = 0.7739760316291208f;
    float sv[3]; sv[0] = s0; sv[1] = 0.f; sv[2] = s2;
    float w1a = w1[i], w1b = w1[512 + i], bb = b1[i];
    #pragma unroll
    for (int j = 0; j < 9; j++) {
        float t0 = sv[j / 3], t1 = sv[j % 3];
        hid[j][i] = fmaxf(t0 * w1a + t1 * w1b + bb, 0.f);
    }
    __syncthreads();
    if (i < 54) {
        int he = i / 9, t = i % 9, j = 8 - t;
        float acc = 0.f;
        for (int u = 0; u < 512; u++) acc += hid[j][u] * w2[u * 6 + he];
        rb[he * 9 + t] = 16.f / (1.f + expf(-acc));
    }
}

// ---------------- prep: x->bf16, qkv_w^T->bf16, proj_w^T->bf16 ----------------
__global__ __launch_bounds__(256)
void prep_kernel(const float* __restrict__ x, const float* __restrict__ qkv_w,
                 const float* __restrict__ proj_w,
                 unsigned short* __restrict__ xs, unsigned short* __restrict__ Bt,
                 unsigned short* __restrict__ Bt2)
{
    int tid = blockIdx.x * 256 + threadIdx.x;
    int stride = gridDim.x * 256;
    int total_x4 = PIX * 192 / 4;
    for (int i = tid; i < total_x4; i += stride) {
        float4 v = ((const float4*)x)[i];
        ushort4v o;
        o.x = f2bf(v.x); o.y = f2bf(v.y); o.z = f2bf(v.z); o.w = f2bf(v.w);
        ((ushort4v*)xs)[i] = o;
    }
    for (int i = tid; i < 576 * 192; i += stride) {
        int n = i / 192, k = i - n * 192;
        Bt[i] = f2bf(qkv_w[k * 576 + n]);
    }
    for (int i = tid; i < 192 * 192; i += stride) {
        int n = i / 192, k = i - n * 192;
        Bt2[i] = f2bf(proj_w[k * 192 + n]);
    }
}

// ---------------- MFMA bf16 GEMM: C = A(MxK=192) * Bt^T + bias ----------------
// A: [M][192] bf16 row-major. Bt: [N][192] bf16 (n-major, k contiguous).
// MODE 0: store C as 8-channel-interleaved planes qkv8[n/8][PIX][8] bf16 + qkv bias.
// MODE 1: store fp32 [m][192] + bias.
template<int MODE>
__global__ __launch_bounds__(256)
void mfma_gemm_kernel(const unsigned short* __restrict__ Abf,
                      const unsigned short* __restrict__ Btb,
                      void* __restrict__ Cout,
                      const float* __restrict__ bias0,
                      const float* __restrict__ bias1)
{
    const int K = 192;
    __shared__ short smem[128 * 64 + 64 * 64];   // As | Bs ; reused as epilogue buffer
    short* As = smem;
    short* Bs = smem + 128 * 64;
    int tid = threadIdx.x;
    int m0 = blockIdx.y * 128;
    int n0 = blockIdx.x * 64;
    int lane = tid & 63, wid = tid >> 6;
    int wm = wid >> 1, wn = wid & 1;
    int lr = lane & 15, lk = lane >> 4;

    float4v acc[4][2];
    #pragma unroll
    for (int a = 0; a < 4; a++)
        #pragma unroll
        for (int b = 0; b < 2; b++)
            #pragma unroll
            for (int e = 0; e < 4; e++) acc[a][b][e] = 0.f;

    int sr = tid >> 3;          // 0..31
    int sc = tid & 7;           // 0..7 (16B chunk)
    for (int k0 = 0; k0 < K; k0 += 64) {
        #pragma unroll
        for (int i = 0; i < 4; i++) {
            int r = sr + i * 32;
            short8v v = *(const short8v*)(Abf + (size_t)(m0 + r) * K + k0 + sc * 8);
            *(short8v*)(As + r * 64 + ((sc ^ (r & 7)) * 8)) = v;
        }
        #pragma unroll
        for (int i = 0; i < 2; i++) {
            int r = sr + i * 32;
            short8v v = *(const short8v*)(Btb + (size_t)(n0 + r) * K + k0 + sc * 8);
            *(short8v*)(Bs + r * 64 + ((sc ^ (r & 7)) * 8)) = v;
        }
        __syncthreads();
        #pragma unroll
        for (int ks = 0; ks < 2; ks++) {
            short8v af[4], bf[2];
            #pragma unroll
            for (int fm = 0; fm < 4; fm++) {
                int r = wm * 64 + fm * 16 + lr;
                int c = (ks * 4 + lk) ^ (r & 7);
                af[fm] = *(const short8v*)(As + r * 64 + c * 8);
            }
            #pragma unroll
            for (int fn = 0; fn < 2; fn++) {
                int r = wn * 32 + fn * 16 + lr;
                int c = (ks * 4 + lk) ^ (r & 7);
                bf[fn] = *(const short8v*)(Bs + r * 64 + c * 8);
            }
            #pragma unroll
            for (int fm = 0; fm < 4; fm++)
                #pragma unroll
                for (int fn = 0; fn < 2; fn++)
                    acc[fm][fn] = __builtin_amdgcn_mfma_f32_16x16x32_bf16(
                        af[fm], bf[fn], acc[fm][fn], 0, 0, 0);
        }
        __syncthreads();
    }

    if (MODE == 0) {
        // stage C tile bf16 into LDS as T[m 0..127][n 0..63], row pad 74
        const int TP = 74;
        unsigned short* T = (unsigned short*)smem;
        #pragma unroll
        for (int fm = 0; fm < 4; fm++) {
            #pragma unroll
            for (int fn = 0; fn < 2; fn++) {
                int n = wn * 32 + fn * 16 + lr;
                int gn = n0 + n;
                float bv = (gn < 192) ? bias0[gn] : ((gn < 384) ? 0.f : bias1[gn - 384]);
                #pragma unroll
                for (int e = 0; e < 4; e++) {
                    int m = wm * 64 + fm * 16 + lk * 4 + e;
                    T[m * TP + n] = f2bf(acc[fm][fn][e] + bv);
                }
            }
        }
        __syncthreads();
        unsigned short* qkv8 = (unsigned short*)Cout;
        #pragma unroll
        for (int i = 0; i < 4; i++) {
            int u = tid + 256 * i;            // 0..1023
            int m = u & 127, cgl = u >> 7;    // 8 local channel-groups
            short8v vv = *(const short8v*)(T + m * TP + cgl * 8);
            int gcg = (n0 >> 3) + cgl;
            *(short8v*)(qkv8 + ((size_t)gcg * PIX + m0 + m) * 8) = vv;
        }
    } else {
        float* outp = (float*)Cout;
        #pragma unroll
        for (int fm = 0; fm < 4; fm++) {
            #pragma unroll
            for (int fn = 0; fn < 2; fn++) {
                int n = n0 + wn * 32 + fn * 16 + lr;
                float bv = bias0[n];
                #pragma unroll
                for (int e = 0; e < 4; e++) {
                    int m = m0 + wm * 64 + fm * 16 + lk * 4 + e;
                    outp[(size_t)m * 192 + n] = acc[fm][fn][e] + bv;
                }
            }
        }
    }
}

// ---------------- fused: depthwise(k,v) + cosine attention + PV -----------------------
// Block = 256 thr = 4 waves per (head, 32x2 pixel tile). Wave w handles channel group
// he*4+w (8 channels). qkv8 layout: 16B per pixel per group -> all taps load up-front,
// coalesced 1KB/wave. Per-head reductions combined via LDS float atomics.
__global__ __launch_bounds__(256)
void fused5_kernel(const unsigned short* __restrict__ qkv8, const float* __restrict__ deform,
                   const float* __restrict__ scale, const float* __restrict__ rb,
                   unsigned short* __restrict__ attnS)
{
    __shared__ float red[64][21];   // per-pixel: qk[0..8], kn[9..17], qn2[18]

    int id = blockIdx.x;              // 4 b * 6 he * 48 ypairs * 3 strips = 3456
    int strip = id % 3;
    int yp = (id / 3) % 48;
    int he = (id / 144) % 6;
    int b = id / 864;
    int tid = threadIdx.x;
    int l = tid & 63;
    int wsub = tid >> 6;              // 0..3 channel-group split
    int X = strip * 32 + (l & 31);
    int Y = yp * 2 + (l >> 5);
    int pimg = Y * 96 + X;
    size_t ibase = (size_t)b * IMG;

    for (int i = tid; i < 64 * 21; i += 256) (&red[0][0])[i] = 0.f;
    __syncthreads();

    int c0 = __builtin_amdgcn_readfirstlane(he * 32 + wsub * 8);
    int qg = c0 >> 3;                 // 0..23
    const uint4v* qp = (const uint4v*)(qkv8 + ((size_t)qg * PIX + ibase) * 8);
    const uint4v* kp = (const uint4v*)(qkv8 + ((size_t)(24 + qg) * PIX + ibase) * 8);
    const uint4v* vp = (const uint4v*)(qkv8 + ((size_t)(48 + qg) * PIX + ibase) * 8);

    int off[9];
    unsigned okm = 0;
    #pragma unroll
    for (int pos = 0; pos < 9; pos++) {
        int dy = pos / 3 - 1, dx = pos % 3 - 1;
        int yy = Y + dy, xx = X + dx;
        bool ok = (yy >= 0) && (yy < 96) && (xx >= 0) && (xx < 96);
        okm |= (ok ? 1u : 0u) << pos;
        off[pos] = ok ? (yy * 96 + xx) : pimg;
    }

    // ---- pass 1 loads: q + 9 k-taps, all issued up front (16B each, coalesced) ----
    uint4v qd = qp[pimg];
    uint4v kd[9];
    #pragma unroll
    for (int pos = 0; pos < 9; pos++) kd[pos] = kp[off[pos]];
    #pragma unroll
    for (int pos = 0; pos < 9; pos++)
        if (!((okm >> pos) & 1)) { kd[pos].x = 0; kd[pos].y = 0; kd[pos].z = 0; kd[pos].w = 0; }

    float qk[9], kn[9];
    #pragma unroll
    for (int t = 0; t < 9; t++) { qk[t] = 0.f; kn[t] = 0.f; }
    float qn2 = 0.f;

    #pragma unroll
    for (int ci = 0; ci < 8; ci++) {
        int c = c0 + ci;
        unsigned qw = ((const unsigned*)&qd)[ci >> 1];
        float q = (ci & 1) ? bfhi(qw) : bflo(qw);
        qn2 = fmaf(q, q, qn2);
        float kin[9];
        #pragma unroll
        for (int pos = 0; pos < 9; pos++) {
            unsigned dw = ((const unsigned*)&kd[pos])[ci >> 1];
            kin[pos] = (ci & 1) ? bfhi(dw) : bflo(dw);
        }
        float ktap[9];
        #pragma unroll
        for (int t = 0; t < 9; t++) ktap[t] = kin[t];
        #pragma unroll
        for (int pos = 0; pos < 9; pos++) {
            const float* wr = deform + ((size_t)pos * 192 + c) * 9;   // wave-uniform
            #pragma unroll
            for (int t = 0; t < 9; t++) ktap[t] = fmaf(kin[pos], wr[t], ktap[t]);
        }
        #pragma unroll
        for (int t = 0; t < 9; t++) {
            qk[t] = fmaf(q, ktap[t], qk[t]);
            kn[t] = fmaf(ktap[t], ktap[t], kn[t]);
        }
    }

    // ---- issue pass-2 v loads now; latency hides under reduce+softmax ----
    uint4v vd[9];
    #pragma unroll
    for (int pos = 0; pos < 9; pos++) vd[pos] = vp[off[pos]];

    #pragma unroll
    for (int t = 0; t < 9; t++) atomicAdd(&red[l][t], qk[t]);
    #pragma unroll
    for (int t = 0; t < 9; t++) atomicAdd(&red[l][9 + t], kn[t]);
    atomicAdd(&red[l][18], qn2);

    #pragma unroll
    for (int pos = 0; pos < 9; pos++)
        if (!((okm >> pos) & 1)) { vd[pos].x = 0; vd[pos].y = 0; vd[pos].z = 0; vd[pos].w = 0; }
    __syncthreads();

    // ---- softmax (redundant per wave, identical inputs) ----
    float qn = rsqrtf(fmaxf(red[l][18], EPS));
    float es = expf(scale[he]);
    float w[9];
    float m = -1e30f;
    #pragma unroll
    for (int t = 0; t < 9; t++) {
        float lg = es * qn * red[l][t] * rsqrtf(fmaxf(red[l][9 + t], EPS));
        lg += (((okm >> t) & 1) ? 0.f : -100.f) + rb[he * 9 + t];
        w[t] = lg;
        m = fmaxf(m, lg);
    }
    float ssum = 0.f;
    #pragma unroll
    for (int t = 0; t < 9; t++) { w[t] = expf(w[t] - m); ssum += w[t]; }
    float inv = 1.f / ssum;
    #pragma unroll
    for (int t = 0; t < 9; t++) w[t] *= inv;

    // ---- pass 2: v depthwise folded through softmax weights ----
    unsigned short o8[8];
    #pragma unroll
    for (int ci = 0; ci < 8; ci++) {
        int c = c0 + ci;
        float vin[9];
        #pragma unroll
        for (int pos = 0; pos < 9; pos++) {
            unsigned dw = ((const unsigned*)&vd[pos])[ci >> 1];
            vin[pos] = (ci & 1) ? bfhi(dw) : bflo(dw);
        }
        float acc = 0.f;
        #pragma unroll
        for (int pos = 0; pos < 9; pos++) {
            const float* wr = deform + ((size_t)pos * 192 + c) * 9;   // wave-uniform
            float sp = w[pos];
            #pragma unroll
            for (int t = 0; t < 9; t++) sp = fmaf(w[t], wr[t], sp);
            acc = fmaf(vin[pos], sp, acc);
        }
        o8[ci] = f2bf(acc);
    }
    short8v ov;
    #pragma unroll
    for (int ci = 0; ci < 8; ci++) ov[ci] = (short)o8[ci];
    *(short8v*)(attnS + (ibase + pimg) * 192 + c0) = ov;
}

extern "C" void kernel_launch(void* const* d_in, const int* in_sizes, int n_in,
                              void* d_out, int out_size, void* d_ws, size_t ws_size,
                              hipStream_t stream) {
    const float* x       = (const float*)d_in[0];
    const float* qkv_w   = (const float*)d_in[1];
    const float* q_bias  = (const float*)d_in[2];
    const float* v_bias  = (const float*)d_in[3];
    const float* deform  = (const float*)d_in[4];
    const float* scale   = (const float*)d_in[5];
    const float* cpb_w1  = (const float*)d_in[6];
    const float* cpb_b1  = (const float*)d_in[7];
    const float* cpb_w2  = (const float*)d_in[8];
    const float* proj_w  = (const float*)d_in[9];
    const float* proj_b  = (const float*)d_in[10];
    float* out = (float*)d_out;

    char* ws = (char*)d_ws;
    float*          rb    = (float*)ws;                               // 256 B
    unsigned short* xs    = (unsigned short*)(ws + 256);              // PIX*192*2 = 14,155,776 B
    unsigned short* Bt    = (unsigned short*)(ws + 256 + 14155776);   // 221,184 B
    unsigned short* Bt2   = (unsigned short*)(ws + 256 + 14155776 + 221184);          // 73,728 B
    unsigned short* qkv8  = (unsigned short*)(ws + 256 + 14155776 + 221184 + 73728);  // 42,467,328 B
    unsigned short* attnS = (unsigned short*)(ws + 256 + 14155776 + 221184 + 73728 + 42467328); // 14,155,776 B

    relbias_kernel<<<1, 512, 0, stream>>>(cpb_w1, cpb_b1, cpb_w2, rb);
    prep_kernel<<<2048, 256, 0, stream>>>(x, qkv_w, proj_w, xs, Bt, Bt2);
    mfma_gemm_kernel<0><<<dim3(576 / 64, PIX / 128), 256, 0, stream>>>(
        xs, Bt, (void*)qkv8, q_bias, v_bias);
    fused5_kernel<<<3456, 256, 0, stream>>>(qkv8, deform, scale, rb, attnS);
    mfma_gemm_kernel<1><<<dim3(192 / 64, PIX / 128), 256, 0, stream>>>(
        attnS, Bt2, (void*)out, proj_b, nullptr);
}